// Round 7
// baseline (525.163 us; speedup 1.0000x reference)
//
#include <hip/hip_runtime.h>
#include <hip/hip_bf16.h>
#include <cstdint>

// Problem: B=2, S=2048, D=2048, HQ=16, DH=128, single shared K/V head (GQA).
// Inputs/outputs fp32 (runtime-detected); compute bf16 MFMA.
// 4 dispatches: prep -> gemm(QKV, fused V^T epi) -> flash(v5 kv-split) -> gemm(out).

typedef __bf16 bf16;
typedef __bf16 bf16x8 __attribute__((ext_vector_type(8)));
typedef __bf16 bf16x4 __attribute__((ext_vector_type(4)));
typedef float  floatx4 __attribute__((ext_vector_type(4)));

__device__ __forceinline__ floatx4 mfma16(bf16x8 a, bf16x8 b, floatx4 c) {
  return __builtin_amdgcn_mfma_f32_16x16x32_bf16(a, b, c, 0, 0, 0);
}

__device__ __forceinline__ void glds16(const bf16* g, bf16* l) {
  __builtin_amdgcn_global_load_lds(
      (const __attribute__((address_space(1))) unsigned int*)(const void*)g,
      (__attribute__((address_space(3))) unsigned int*)(void*)l, 16, 0, 0);
}

// LDS-only drain + barrier: register-destined global prefetch stays in flight.
__device__ __forceinline__ void lgkm_barrier() {
  asm volatile("s_waitcnt lgkmcnt(0)\n\ts_barrier" ::: "memory");
}

// ---------------------------------------------------------------------------
// Mega-prep: per-block dtype probe, then region work by blockIdx.x:
// [0,2048)       x convert (4 grid passes)
// [2048,6144)    Wq^T   (64x64 tiles)
// [6144,10240)   Wo^T
// [10240,10496)  Wk^T   (4x64 tiles)
// [10496,10752)  Wv^T
// [10752]        biases + flag store
// ---------------------------------------------------------------------------
__global__ __launch_bounds__(256) void prep_kernel(
    const void* __restrict__ xs, const void* __restrict__ wq,
    const void* __restrict__ wk, const void* __restrict__ wv,
    const void* __restrict__ wo, const void* __restrict__ bq,
    const void* __restrict__ bk, const void* __restrict__ bv,
    const void* __restrict__ bo, bf16* __restrict__ x_c,
    bf16* __restrict__ WqkvT, bf16* __restrict__ WoT,
    bf16* __restrict__ bqkv, bf16* __restrict__ bo_c, int* __restrict__ flag) {
  __shared__ int cnt;
  __shared__ bf16 tile[32][33];
  if (threadIdx.x == 0) cnt = 0;
  __syncthreads();
  {  // dtype probe (same 8192-u16 scan every block; x region is hot in cache)
    const unsigned short* u = (const unsigned short*)xs;
    int bad = 0;
    for (int i = threadIdx.x; i < 8192; i += 256) {
      const unsigned e = (u[i] >> 7) & 0xFF;
      if (e >= 0x90 || e <= 0x5F) bad++;
    }
    atomicAdd(&cnt, bad);
  }
  __syncthreads();
  const int f = (cnt > 256) ? 1 : 0;
  const int blk = blockIdx.x;

  if (blk < 2048) {  // x convert: 2,097,152 vec4 groups = 2048*256*4 exactly
    int i = blk * 256 + threadIdx.x;
    if (f) {
      const float4* s = (const float4*)xs;
#pragma unroll
      for (int p = 0; p < 4; ++p) {
        const float4 v = s[i + p * 524288];
        bf16x4 o = {(bf16)v.x, (bf16)v.y, (bf16)v.z, (bf16)v.w};
        *(bf16x4*)(x_c + (size_t)(i + p * 524288) * 4) = o;
      }
    } else {
      const ushort4* s = (const ushort4*)xs;
#pragma unroll
      for (int p = 0; p < 4; ++p)
        ((ushort4*)x_c)[i + p * 524288] = s[i + p * 524288];
    }
    return;
  }
  if (blk == 10752) {  // biases + flag
    if (threadIdx.x == 0) *flag = f;
    const void* ss[4] = {bq, bk, bv, bo};
    bf16* dd[4] = {bqkv, bqkv + 2048, bqkv + 2176, bo_c};
    const int nn[4] = {2048, 128, 128, 2048};
#pragma unroll
    for (int a = 0; a < 4; ++a)
      for (int i = threadIdx.x; i < nn[a]; i += 256)
        dd[a][i] = f ? (bf16)((const float*)ss[a])[i] : ((const bf16*)ss[a])[i];
    return;
  }
  // transpose regions
  const void* src;
  bf16* dst;
  int bx, by, C;
  if (blk < 6144)       { int t = blk - 2048;  src = wq; dst = WqkvT;             bx = t & 63; by = t >> 6; C = 2048; }
  else if (blk < 10240) { int t = blk - 6144;  src = wo; dst = WoT;               bx = t & 63; by = t >> 6; C = 2048; }
  else if (blk < 10496) { int t = blk - 10240; src = wk; dst = WqkvT + 2048*2048; bx = t & 3;  by = t >> 2; C = 128; }
  else                  { int t = blk - 10496; src = wv; dst = WqkvT + 2176*2048; bx = t & 3;  by = t >> 2; C = 128; }
  const int R = 2048;
  const int tx = threadIdx.x & 31, ty = threadIdx.x >> 5;
  const int x0 = bx * 32, y0 = by * 32;
  if (f) {
    const float* s = (const float*)src;
#pragma unroll
    for (int i = 0; i < 32; i += 8)
      tile[ty + i][tx] = (bf16)s[(size_t)(y0 + ty + i) * C + x0 + tx];
  } else {
    const bf16* s = (const bf16*)src;
#pragma unroll
    for (int i = 0; i < 32; i += 8)
      tile[ty + i][tx] = s[(size_t)(y0 + ty + i) * C + x0 + tx];
  }
  __syncthreads();
#pragma unroll
  for (int i = 0; i < 32; i += 8)
    dst[(size_t)(x0 + ty + i) * R + y0 + tx] = tile[tx][ty + i];
}

// ---------------------------------------------------------------------------
// C[M][N] = A[M][K] @ Bt[N][K]^T (+bias). m97 128x128 tile, BK=32, 4 waves.
// VTout: if non-null, blocks at n0==2176 also write V^T[col-2176][row] (fused
// transv). f32out: flag ptr for fp32 stores (final output), else bf16.
// ---------------------------------------------------------------------------
__global__ __launch_bounds__(256, 2) void gemm_bt_kernel(
    const bf16* __restrict__ A, const bf16* __restrict__ Bt,
    const bf16* __restrict__ bias, void* __restrict__ Cout,
    const int M, const int N, const int K, const int bias_mode,
    const int* __restrict__ f32out, bf16* __restrict__ VTout) {
  __shared__ __align__(16) bf16 ldsA[128 * 32];
  __shared__ __align__(16) bf16 ldsB[128 * 32];
  const int tid = threadIdx.x, lane = tid & 63, wave = tid >> 6;
  const int l15 = lane & 15, quad = lane >> 4;
  const int m0 = blockIdx.y * 128, n0 = blockIdx.x * 128;
  const int wm = wave >> 1, wn = wave & 1;
  const int f32 = f32out ? *f32out : 0;

  floatx4 acc[4][4];
  const floatx4 z4 = {0.f, 0.f, 0.f, 0.f};
#pragma unroll
  for (int i = 0; i < 4; ++i)
#pragma unroll
    for (int j = 0; j < 4; ++j) acc[i][j] = z4;

  const int srow = (lane >> 2);
  const int scol = (lane & 3) * 8;

  for (int k0 = 0; k0 < K; k0 += 32) {
    __syncthreads();
#pragma unroll
    for (int j = 0; j < 2; ++j) {
      const int chunk = wave * 2 + j;
      glds16(A + (size_t)(m0 + chunk * 16 + srow) * K + k0 + scol, ldsA + chunk * 512);
      glds16(Bt + (size_t)(n0 + chunk * 16 + srow) * K + k0 + scol, ldsB + chunk * 512);
    }
    __syncthreads();
    bf16x8 af[4], bfr[4];
#pragma unroll
    for (int i = 0; i < 4; ++i) {
      af[i]  = *(const bf16x8*)(ldsA + (wm * 64 + i * 16 + l15) * 32 + quad * 8);
      bfr[i] = *(const bf16x8*)(ldsB + (wn * 64 + i * 16 + l15) * 32 + quad * 8);
    }
#pragma unroll
    for (int mi = 0; mi < 4; ++mi)
#pragma unroll
      for (int ni = 0; ni < 4; ++ni)
        acc[mi][ni] = mfma16(af[mi], bfr[ni], acc[mi][ni]);
  }

#pragma unroll
  for (int mi = 0; mi < 4; ++mi) {
    const int row0 = m0 + wm * 64 + mi * 16 + quad * 4;
#pragma unroll
    for (int ni = 0; ni < 4; ++ni) {
      const int col = n0 + wn * 64 + ni * 16 + l15;
      const float badd = (bias_mode == 1) ? (float)bias[col] : 0.f;
      float vv[4];
#pragma unroll
      for (int r = 0; r < 4; ++r) {
        float v = acc[mi][ni][r] + badd;
        if (bias_mode == 2) v += (float)bias[row0 + r];
        vv[r] = v;
        const size_t idx = (size_t)(row0 + r) * N + col;
        if (f32) ((float*)Cout)[idx] = v;
        else     ((bf16*)Cout)[idx]  = (bf16)v;
      }
      if (VTout && n0 == 2176) {  // fused V^T write (V cols 2176..2303)
        bf16x4 t4 = {(bf16)vv[0], (bf16)vv[1], (bf16)vv[2], (bf16)vv[3]};
        *(bf16x4*)(VTout + (size_t)(col - 2176) * 4096 + row0) = t4;
      }
    }
  }
}

// ---------------------------------------------------------------------------
// Flash v5 — kv-split for occupancy AND low LDS traffic (round-6 diagnosis:
// v3=LDS-BW-bound @16 waves, v4=latency-bound @8 waves).
// 512 thr = 8 waves. qw=wave&3 owns 32 q rows; par=wave>>2 owns kv parity.
// Round R: stage kv [R*64, R*64+64); group par computes 32-kv tile at
// R*64+par*32. Constant-shift softmax => partials additive; O/l merged
// pairwise through LDS at the end. LDS: K 2x8K + VT 2x8K + P 8x2K = 48 KB.
// Register prefetch of next round's staging (2 nk + 2 nv uint4/lane).
// ---------------------------------------------------------------------------
__global__ __launch_bounds__(512, 4) void flash_kernel(
    const bf16* __restrict__ Cqkv,  // [4096][2304]: Q cols 0..2047, K 2048..2175
    const bf16* __restrict__ VTg,   // [128][4096]
    bf16* __restrict__ Og) {        // [4096][2048]
  __shared__ __align__(16) bf16 lds_all[24576];  // 48 KB
  bf16* ldsK  = lds_all;          // [2][32 kv][128 d] swizzled granules
  bf16* ldsVT = lds_all + 8192;   // [2][128 d][32 kv] linear
  bf16* ldsP  = lds_all + 16384;  // 8 waves x [32 q][32 kv] swizzled

  const int tid = threadIdx.x, lane = tid & 63, wave = tid >> 6;
  const int l15 = lane & 15, quad = lane >> 4;
  const int qw = wave & 3, par = wave >> 2;
  const int qb = blockIdx.x, bh = blockIdx.y;
  const int b = bh >> 4, h = bh & 15;

  // Q fragments direct from global (B-op: n=l15, k=quad*8+j)
  bf16x8 qfrag[2][4];
  {
    const bf16* qbase = Cqkv + (size_t)(b * 2048 + qb * 128 + qw * 32) * 2304 + h * 128;
#pragma unroll
    for (int qi = 0; qi < 2; ++qi)
#pragma unroll
      for (int kf = 0; kf < 4; ++kf)
        qfrag[qi][kf] =
            *(const bf16x8*)(qbase + (size_t)(qi * 16 + l15) * 2304 + kf * 32 + quad * 8);
  }

  const bf16* kb  = Cqkv + 2048 + (size_t)(b * 2048) * 2304;
  const bf16* vtb = VTg + (size_t)b * 2048;
  bf16* ldsPw = ldsP + wave * 1024;
  const bf16* ldsKg  = ldsK + par * 4096;   // this group's K tile
  const bf16* ldsVTg = ldsVT + par * 4096;  // this group's VT tile

  // staging geometry: 2048 16B-slots (K 1024 + V 1024), 4 per lane
  const bf16* ksrc[2]; bf16* kdst[2];
  const bf16* vsrc[2]; bf16* vdst[2];
#pragma unroll
  for (int j = 0; j < 2; ++j) {
    const int sk = wave * 128 + j * 64 + lane;          // [0,1024)
    const int kp = sk >> 9, s = sk & 511;
    const int row = s >> 4, g = s & 15, gg = g ^ (row & 15);
    kdst[j] = ldsK + kp * 4096 + s * 8;
    ksrc[j] = kb + (size_t)(kp * 32 + row) * 2304 + gg * 8;  // + kv0*2304/row
    const int sv = wave * 128 + j * 64 + lane;
    const int vp = sv >> 9, sv2 = sv & 511;
    const int d = sv2 >> 2, vg = sv2 & 3;
    vdst[j] = ldsVT + vp * 4096 + sv2 * 8;
    vsrc[j] = vtb + (size_t)d * 4096 + vp * 32 + vg * 8;     // + kv0
  }

  // stage tile-pair 0
  uint4 nk[2], nv[2];
#pragma unroll
  for (int j = 0; j < 2; ++j) { nk[j] = *(const uint4*)ksrc[j]; nv[j] = *(const uint4*)vsrc[j]; }
#pragma unroll
  for (int j = 0; j < 2; ++j) { *(uint4*)kdst[j] = nk[j]; *(uint4*)vdst[j] = nv[j]; }
  lgkm_barrier();

  floatx4 oacc[2][8];
  const floatx4 z4 = {0.f, 0.f, 0.f, 0.f};
#pragma unroll
  for (int qi = 0; qi < 2; ++qi)
#pragma unroll
    for (int ni = 0; ni < 8; ++ni) oacc[qi][ni] = z4;
  float lrun[2] = {0.f, 0.f};
  const float c1  = 0.12751745f;  // (1/sqrt(128)) * log2(e)
  const float mu2 = 4.3280850f;   // 3 * log2(e)

  for (int it = 0; it < 32; ++it) {
    if (it < 31) {  // prefetch next tile-pair (in flight across compute)
#pragma unroll
      for (int j = 0; j < 2; ++j) {
        ksrc[j] += 64 * 2304; vsrc[j] += 64;
        nk[j] = *(const uint4*)ksrc[j];
        nv[j] = *(const uint4*)vsrc[j];
      }
    }

    // ---- S^T = K.Q^T over this group's 32-kv tile ----
    floatx4 sacc[2][2];
    sacc[0][0] = z4; sacc[0][1] = z4; sacc[1][0] = z4; sacc[1][1] = z4;
#pragma unroll
    for (int kf = 0; kf < 4; ++kf) {
      const int gg = (kf * 4 + quad) ^ l15;
#pragma unroll
      for (int kvi = 0; kvi < 2; ++kvi) {
        bf16x8 af = *(const bf16x8*)(ldsKg + (kvi * 16 + l15) * 128 + gg * 8);
        sacc[kvi][0] = mfma16(af, qfrag[0][kf], sacc[kvi][0]);
        sacc[kvi][1] = mfma16(af, qfrag[1][kf], sacc[kvi][1]);
      }
    }

    // ---- P = exp2(s*c1 - mu2) -> LDS (swizzled b64), l accumulate ----
    float rs[2] = {0.f, 0.f};
#pragma unroll
    for (int qi = 0; qi < 2; ++qi) {
#pragma unroll
      for (int kvi = 0; kvi < 2; ++kvi) {
        bf16x4 pv;
#pragma unroll
        for (int r = 0; r < 4; ++r) {
          const float p = __builtin_amdgcn_exp2f(fmaf(sacc[kvi][qi][r], c1, -mu2));
          rs[qi] += p;
          pv[r] = (bf16)p;
        }
        const int gg = (kvi * 2 + (quad >> 1)) ^ (l15 & 3);
        *(bf16x4*)(ldsPw + (qi * 16 + l15) * 32 + gg * 8 + (quad & 1) * 4) = pv;
      }
    }
#pragma unroll
    for (int qi = 0; qi < 2; ++qi) {
      float r2 = rs[qi];
      r2 += __shfl_xor(r2, 16);
      r2 += __shfl_xor(r2, 32);
      lrun[qi] += r2;
    }

    asm volatile("s_waitcnt lgkmcnt(0)" ::: "memory");  // same-wave P W->R

    // ---- O += P.V (one 32-k MFMA per (qi,ni); vf shared across qi) ----
    {
      const int ggp = quad ^ (l15 & 3);
      bf16x8 pf0 = *(const bf16x8*)(ldsPw + l15 * 32 + ggp * 8);
      bf16x8 pf1 = *(const bf16x8*)(ldsPw + (16 + l15) * 32 + ggp * 8);
#pragma unroll
      for (int ni = 0; ni < 8; ++ni) {
        bf16x8 vf = *(const bf16x8*)(ldsVTg + (ni * 16 + l15) * 32 + quad * 8);
        oacc[0][ni] = mfma16(pf0, vf, oacc[0][ni]);
        oacc[1][ni] = mfma16(pf1, vf, oacc[1][ni]);
      }
    }

    if (it < 31) {  // rotate staged tiles
      lgkm_barrier();
#pragma unroll
      for (int j = 0; j < 2; ++j) { *(uint4*)kdst[j] = nk[j]; *(uint4*)vdst[j] = nv[j]; }
      lgkm_barrier();
    }
  }

  // ---- merge parity groups: l then O (pairwise via LDS) ----
  float* lsh = (float*)ldsP;       // 128 floats (P dead)
  float* osh = (float*)lds_all;    // 32KB staging (K/VT dead)
  lgkm_barrier();
  if (par == 1 && quad == 0) {
    lsh[qw * 32 + l15] = lrun[0];
    lsh[qw * 32 + 16 + l15] = lrun[1];
  }
  lgkm_barrier();
  if (par == 0) {
    lrun[0] += lsh[qw * 32 + l15];
    lrun[1] += lsh[qw * 32 + 16 + l15];
  }
  // pass 0: waves 4,5 -> 0,1 ; pass 1: waves 6,7 -> 2,3
#pragma unroll
  for (int pass = 0; pass < 2; ++pass) {
    lgkm_barrier();
    if (par == 1 && (qw >> 1) == pass) {
      float* dst = osh + (qw & 1) * 4096;
#pragma unroll
      for (int qi = 0; qi < 2; ++qi)
#pragma unroll
        for (int ni = 0; ni < 8; ++ni)
          *(floatx4*)(dst + (qi * 8 + ni) * 256 + lane * 4) = oacc[qi][ni];
    }
    lgkm_barrier();
    if (par == 0 && (qw >> 1) == pass) {
      const float* src = osh + (qw & 1) * 4096;
#pragma unroll
      for (int qi = 0; qi < 2; ++qi)
#pragma unroll
        for (int ni = 0; ni < 8; ++ni)
          oacc[qi][ni] += *(const floatx4*)(src + (qi * 8 + ni) * 256 + lane * 4);
    }
  }

  // ---- epilogue (group A only): O / l ----
  if (par == 0) {
#pragma unroll
    for (int qi = 0; qi < 2; ++qi) {
      float inv[4];
#pragma unroll
      for (int r = 0; r < 4; ++r) inv[r] = 1.0f / __shfl(lrun[qi], quad * 4 + r);
      const size_t row0 = (size_t)(b * 2048 + qb * 128 + qw * 32 + qi * 16 + quad * 4);
#pragma unroll
      for (int ni = 0; ni < 8; ++ni) {
        const size_t base = row0 * 2048 + h * 128 + ni * 16 + l15;
#pragma unroll
        for (int r = 0; r < 4; ++r)
          Og[base + (size_t)r * 2048] = (bf16)(oacc[qi][ni][r] * inv[r]);
      }
    }
  }
}

// ---------------------------------------------------------------------------
extern "C" void kernel_launch(void* const* d_in, const int* in_sizes, int n_in,
                              void* d_out, int out_size, void* d_ws, size_t ws_size,
                              hipStream_t stream) {
  (void)in_sizes; (void)n_in; (void)out_size; (void)ws_size;
  char* ws = (char*)d_ws;
  int*  flag   = (int*)ws;                    // [0,1024)
  bf16* x_c    = (bf16*)(ws + 1024);          // 16 MB; Og overlays later
  bf16* Og     = x_c;
  bf16* WqkvT  = (bf16*)(ws + 16778240);      // [2304][2048] 9.4 MB
  bf16* WoT    = (bf16*)(ws + 26215424);      // [2048][2048] 8 MB
  bf16* bqkv   = (bf16*)(ws + 34604032);      // [2304]
  bf16* bo_c   = (bf16*)(ws + 34609152);      // [2048]
  bf16* Cqkv   = (bf16*)(ws + 34614272);      // [4096][2304] 18.9 MB
  bf16* VTg    = (bf16*)(ws + 53489664);      // [128][4096] 1 MB

  const dim3 blk(256);
  prep_kernel<<<dim3(10753), blk, 0, stream>>>(
      d_in[0], d_in[1], d_in[3], d_in[5], d_in[7],
      d_in[2], d_in[4], d_in[6], d_in[8],
      x_c, WqkvT, WoT, bqkv, bo_c, flag);

  // QKV = x @ [Wq|Wk|Wv] + bias; block n0==2176 also writes V^T
  gemm_bt_kernel<<<dim3(18, 32), blk, 0, stream>>>(x_c, WqkvT, bqkv, Cqkv,
                                                   4096, 2304, 2048, 1, nullptr, VTg);
  // attention
  flash_kernel<<<dim3(16, 32), dim3(512), 0, stream>>>(Cqkv, VTg, Og);
  // out = Og@Wo + bo (fp32 store per flag)
  gemm_bt_kernel<<<dim3(16, 32), blk, 0, stream>>>(Og, WoT, bo_c, d_out,
                                                   4096, 2048, 2048, 1, flag, nullptr);
}